// Round 13
// baseline (693.765 us; speedup 1.0000x reference)
//
#include <hip/hip_runtime.h>
#include <hip/hip_bf16.h>
#include <stdint.h>

#define NTOT 65536   // B * N_NODE
#define NNODE 2048
#define CIN 12

__device__ __forceinline__ float bf2f(uint32_t u) {
    union { uint32_t i; float f; } v; v.i = u << 16; return v.f;
}
__device__ __forceinline__ uint16_t f2bf(float f) {
    union { float f; uint32_t i; } v; v.f = f;
    uint32_t x = v.i;
    uint32_t r = x + 0x7fffu + ((x >> 16) & 1u);
    return (uint16_t)(r >> 16);
}
__device__ __forceinline__ float bflo(uint32_t u) { return bf2f(u & 0xffffu); }
__device__ __forceinline__ float bfhi(uint32_t u) { return bf2f(u >> 16); }
__device__ __forceinline__ float sigmf(float x) { return 1.0f / (1.0f + __expf(-x)); }
__device__ __forceinline__ float lrelu(float v) { return v > 0.f ? v : 0.2f * v; }

// ws float offsets (flags[0]=bf16?, flags[1]=edge stride words, flags[2]=gcount)
#define O_WG   16
#define O_AS   1168
#define O_AD   1264
#define O_BIAS 1360
#define O_BIH1 1376
#define O_BHH1 1504
#define O_BIH2 1632
#define O_BHH2 2144
#define O_BLIN 2656
#define O_END  21088

__device__ __forceinline__ void cvt(const void* s, float* d, int i, int bf) {
    d[i] = bf ? bf2f(((const uint16_t*)s)[i]) : ((const float*)s)[i];
}

// ---------- fused: dtype detect + small-tensor conv + zero ----------
__global__ void __launch_bounds__(256) k_pre(
    const void* x, const int* __restrict__ e32,
    const void* wg, const void* as_, const void* ad_, const void* bs,
    const void* b1, const void* bb1, const void* b2, const void* bb2,
    const void* bl, float* __restrict__ ws, int* __restrict__ deg) {
    int tid = threadIdx.x, lane = tid & 63;
    uint32_t u = ((const uint16_t*)x)[2 * lane];
    uint32_t ex = (u >> 7) & 0xFF;
    bool sane = (ex >= 0x60 && ex <= 0x9F) || (u == 0);
    unsigned long long bsx = __ballot(sane);
    bool hi_zero = (e32[2 * lane + 1] == 0);
    unsigned long long bz = __ballot(hi_zero);
    int bf = (__popcll(bsx) >= 52) ? 1 : 0;
    int st = (__popcll(bz) == 64) ? 2 : 1;
    if (blockIdx.x == 0 && tid == 0) {
        ((int*)ws)[0] = bf; ((int*)ws)[1] = st; ((int*)ws)[2] = 0;
    }
    deg[blockIdx.x * 256 + tid] = 0;
    int i = blockIdx.x * 256 + tid;
    if (i < 1152)  { cvt(wg,  ws + O_WG,   i, bf); return; } i -= 1152;
    if (i < 96)    { cvt(as_, ws + O_AS,   i, bf); return; } i -= 96;
    if (i < 96)    { cvt(ad_, ws + O_AD,   i, bf); return; } i -= 96;
    if (i < 12)    { cvt(bs,  ws + O_BIAS, i, bf); return; } i -= 12;
    if (i < 128)   { cvt(b1,  ws + O_BIH1, i, bf); return; } i -= 128;
    if (i < 128)   { cvt(bb1, ws + O_BHH1, i, bf); return; } i -= 128;
    if (i < 512)   { cvt(b2,  ws + O_BIH2, i, bf); return; } i -= 512;
    if (i < 512)   { cvt(bb2, ws + O_BHH2, i, bf); return; } i -= 512;
    if (i < 18432) { cvt(bl,  ws + O_BLIN, i, bf); }
}

// ---------- fused attention scores + edge histogram ----------
__global__ void __launch_bounds__(256) k_nfa(const void* __restrict__ xraw,
                                             const float* __restrict__ Wg,
                                             const float* __restrict__ att,
                                             const int* __restrict__ flags,
                                             const int* __restrict__ e, int E,
                                             int* __restrict__ deg, int* __restrict__ rank,
                                             float* __restrict__ a_s, float* __restrict__ a_d) {
    __shared__ float sx[384];
    __shared__ float sw[1152];
    __shared__ float satt[192];
    __shared__ float sh[3072];
    int tid = threadIdx.x;
    int n0 = blockIdx.x * 32;
    if (flags[0]) {
        const uint32_t* xp = (const uint32_t*)xraw;
        for (int i = tid; i < 192; i += 256) {
            uint32_t u = xp[n0 * 6 + i];
            sx[2 * i] = bflo(u); sx[2 * i + 1] = bfhi(u);
        }
    } else {
        const float* xp = (const float*)xraw;
        for (int i = tid; i < 384; i += 256) sx[i] = xp[n0 * 12 + i];
    }
    for (int i = tid; i < 1152; i += 256) sw[i] = Wg[i];
    if (tid < 192) satt[tid] = att[tid];
    {
        long st = flags[1];
        int chunk = (E + gridDim.x - 1) / gridDim.x;
        int ebase = blockIdx.x * chunk;
        int eend = min(ebase + chunk, E);
        for (int i = ebase + tid; i < eend; i += 256) {
            int d = e[st * (E + i)];
            rank[i] = atomicAdd(&deg[d], 1);
        }
    }
    __syncthreads();
#pragma unroll
    for (int r = 0; r < 12; r++) {
        int idx = r * 256 + tid;
        int n = idx / 96, o = idx % 96;
        float acc = 0.f;
#pragma unroll
        for (int k = 0; k < 12; k++) acc += sx[n * 12 + k] * sw[k * 96 + o];
        sh[idx] = acc;
    }
    __syncthreads();
    {
        int nl = tid >> 3, h = tid & 7;
        const float* hr = sh + nl * 96 + h * 12;
        float s = 0.f, dd = 0.f;
#pragma unroll
        for (int c = 0; c < 12; c++) {
            float v = hr[c];
            s += v * satt[h * 12 + c];
            dd += v * satt[96 + h * 12 + c];
        }
        a_s[n0 * 8 + tid] = s;
        a_d[n0 * 8 + tid] = dd;
    }
}

// ---------- scan: local exclusive scan + atomic global base ----------
__global__ void k_scan(const int* __restrict__ deg, int* __restrict__ offs,
                       int* __restrict__ gcount) {
    __shared__ int s[256];
    __shared__ int base;
    int t = threadIdx.x, i = blockIdx.x * 256 + t;
    int v = deg[i];
    s[t] = v; __syncthreads();
    for (int off = 1; off < 256; off <<= 1) {
        int a = (t >= off) ? s[t - off] : 0;
        __syncthreads();
        s[t] += a;
        __syncthreads();
    }
    if (t == 255) base = atomicAdd(gcount, s[255]);
    __syncthreads();
    offs[i] = base + s[t] - v;
}

__global__ void k_scatter(const int* __restrict__ e, int E, const int* __restrict__ flags,
                          const int* __restrict__ offs, const int* __restrict__ rank,
                          int* __restrict__ ssrc) {
    int i = blockIdx.x * 256 + threadIdx.x;
    if (i < E) {
        long st = flags[1];
        int s = e[st * i];
        int d = e[st * (E + i)];
        ssrc[offs[d] + rank[i]] = s;
    }
}

// ---------- GAT aggregation: aggregate x (12ch), project through Wg per node ----------
__global__ void __launch_bounds__(256) k_agg(
    const void* __restrict__ xraw, const float* __restrict__ WgG,
    const float* __restrict__ a_s, const float* __restrict__ a_d,
    const int* __restrict__ offs, const int* __restrict__ deg,
    const int* __restrict__ ssrc, const float* __restrict__ bias,
    const int* __restrict__ flags, float* __restrict__ gT) {
    __shared__ float swg[1152];
    __shared__ float sres[4][12];
    int tid = threadIdx.x, wave = tid >> 6, lane = tid & 63;
    for (int i = tid; i < 1152; i += 256) swg[i] = WgG[i];
    __syncthreads();
    int node = blockIdx.x * 4 + wave;
    int beg = offs[node], d = deg[node];
    int sub = lane >> 3, h = lane & 7;
    float adh = a_d[node * 8 + h];
    int bf = flags[0];
    float acc[12];
    float wsum = 0.f;
#pragma unroll
    for (int c = 0; c < 12; c++) acc[c] = 0.f;
    if (sub == 0) {
        float w = __expf(lrelu(a_s[node * 8 + h] + adh));
        wsum = w;
        if (bf) {
            const uint2* xp = (const uint2*)((const uint16_t*)xraw + node * 12);
            uint2 u0 = xp[0], u1 = xp[1], u2 = xp[2];
            acc[0] = w * bflo(u0.x); acc[1] = w * bfhi(u0.x);
            acc[2] = w * bflo(u0.y); acc[3] = w * bfhi(u0.y);
            acc[4] = w * bflo(u1.x); acc[5] = w * bfhi(u1.x);
            acc[6] = w * bflo(u1.y); acc[7] = w * bfhi(u1.y);
            acc[8] = w * bflo(u2.x); acc[9] = w * bfhi(u2.x);
            acc[10] = w * bflo(u2.y); acc[11] = w * bfhi(u2.y);
        } else {
            const float4* xp = (const float4*)((const float*)xraw + node * 12);
            float4 v0 = xp[0], v1 = xp[1], v2 = xp[2];
            acc[0] = w * v0.x; acc[1] = w * v0.y; acc[2] = w * v0.z; acc[3] = w * v0.w;
            acc[4] = w * v1.x; acc[5] = w * v1.y; acc[6] = w * v1.z; acc[7] = w * v1.w;
            acc[8] = w * v2.x; acc[9] = w * v2.y; acc[10] = w * v2.z; acc[11] = w * v2.w;
        }
    }
    for (int base = 0; base < d; base += 8) {
        int k = base + sub;
        if (k < d) {
            int s = ssrc[beg + k];
            float w = __expf(lrelu(a_s[s * 8 + h] + adh));
            wsum += w;
            if (bf) {
                const uint2* xp = (const uint2*)((const uint16_t*)xraw + s * 12);
                uint2 u0 = xp[0], u1 = xp[1], u2 = xp[2];
                acc[0] += w * bflo(u0.x); acc[1] += w * bfhi(u0.x);
                acc[2] += w * bflo(u0.y); acc[3] += w * bfhi(u0.y);
                acc[4] += w * bflo(u1.x); acc[5] += w * bfhi(u1.x);
                acc[6] += w * bflo(u1.y); acc[7] += w * bfhi(u1.y);
                acc[8] += w * bflo(u2.x); acc[9] += w * bfhi(u2.x);
                acc[10] += w * bflo(u2.y); acc[11] += w * bfhi(u2.y);
            } else {
                const float4* xp = (const float4*)((const float*)xraw + s * 12);
                float4 v0 = xp[0], v1 = xp[1], v2 = xp[2];
                acc[0] += w * v0.x; acc[1] += w * v0.y; acc[2] += w * v0.z; acc[3] += w * v0.w;
                acc[4] += w * v1.x; acc[5] += w * v1.y; acc[6] += w * v1.z; acc[7] += w * v1.w;
                acc[8] += w * v2.x; acc[9] += w * v2.y; acc[10] += w * v2.z; acc[11] += w * v2.w;
            }
        }
    }
#pragma unroll
    for (int off = 8; off <= 32; off <<= 1) {
        wsum += __shfl_xor(wsum, off, 64);
#pragma unroll
        for (int c = 0; c < 12; c++) acc[c] += __shfl_xor(acc[c], off, 64);
    }
    float invw = 1.f / wsum;
#pragma unroll
    for (int c = 0; c < 12; c++) acc[c] *= invw;
    float p0 = 0.f, p1 = 0.f;
    const float* wcol = swg + h * 12;
#pragma unroll
    for (int k = 0; k < 12; k++) {
        float a = acc[k];
        p0 += a * wcol[k * 96 + sub];
        p1 += a * wcol[k * 96 + sub + 4];
    }
#pragma unroll
    for (int off = 1; off <= 4; off <<= 1) {
        p0 += __shfl_xor(p0, off, 64);
        p1 += __shfl_xor(p1, off, 64);
    }
    if (h == 0) {
        sres[wave][sub] = p0;
        if (sub >= 4) sres[wave][sub + 4] = p1;
    }
    __syncthreads();
    if (tid < 48) {
        int no = tid / 12, c = tid % 12;
        gT[c * NTOT + blockIdx.x * 4 + no] = sres[no][c] * 0.125f + bias[c];
    }
}

// ---------- fused temporal stack: Z1 + LSTM1 + Z2 + LSTM2, one block per batch ----------
__global__ void __launch_bounds__(512) k_tail(
    const float* __restrict__ gT,
    const void* __restrict__ Wih1r, const float* __restrict__ b1i, const float* __restrict__ b1h,
    const void* __restrict__ Whh1r,
    const void* __restrict__ Wih2r, const void* __restrict__ Whh2r,
    const float* __restrict__ b2i, const float* __restrict__ b2h,
    const int* __restrict__ flags, float* __restrict__ h2l) {
    int b = blockIdx.x, tid = threadIdx.x;
    __shared__ __align__(16) float sgv[2048];
    __shared__ __align__(16) float zp[512];      // [0..31] reused as rec1 h-state
    __shared__ float zs1[12 * 128];
    __shared__ __align__(16) float h1s[12 * 32];
    __shared__ float zs2[12 * 512];
    __shared__ __align__(16) float hb[128];
    __shared__ float zb[512];
    int bf = flags[0];

    // ---- Phase A: Z1[t][row] for this batch (4 threads per row) ----
    int row = tid & 127, qq = tid >> 7;
    for (int t = 0; t < 12; t++) {
        for (int v = tid; v < 2048; v += 512) sgv[v] = gT[t * NTOT + b * NNODE + v];
        __syncthreads();
        float acc = 0.f;
        if (bf) {
            const uint4* wp = (const uint4*)((const uint16_t*)Wih1r + row * 2048 + qq * 512);
            const float4* sp = (const float4*)(sgv + qq * 512);
            for (int k = 0; k < 64; k++) {
                uint4 u = wp[k];
                float4 A = sp[2 * k], B = sp[2 * k + 1];
                acc += bflo(u.x) * A.x + bfhi(u.x) * A.y + bflo(u.y) * A.z + bfhi(u.y) * A.w
                     + bflo(u.z) * B.x + bfhi(u.z) * B.y + bflo(u.w) * B.z + bfhi(u.w) * B.w;
            }
        } else {
            const float4* wp = (const float4*)((const float*)Wih1r + row * 2048 + qq * 512);
            const float4* sp = (const float4*)(sgv + qq * 512);
            for (int k = 0; k < 128; k++) {
                float4 w = wp[k], s = sp[k];
                acc += w.x * s.x + w.y * s.y + w.z * s.z + w.w * s.w;
            }
        }
        zp[tid] = acc;
        __syncthreads();
        if (tid < 128)
            zs1[t * 128 + tid] = zp[tid] + zp[tid + 128] + zp[tid + 256] + zp[tid + 384]
                               + b1i[tid] + b1h[tid];
        __syncthreads();
    }

    // ---- Phase B: LSTM1 recurrence on wave 0 (zero barriers) ----
    if (tid < 64) {
        int lane = tid;
        float wA[32], wB[32];
        if (bf) {
            const uint32_t* w1 = (const uint32_t*)Whh1r;
#pragma unroll
            for (int k = 0; k < 16; k++) {
                uint32_t u = w1[lane * 16 + k];
                wA[2 * k] = bflo(u); wA[2 * k + 1] = bfhi(u);
                uint32_t v = w1[(lane + 64) * 16 + k];
                wB[2 * k] = bflo(v); wB[2 * k + 1] = bfhi(v);
            }
        } else {
            const float* w1 = (const float*)Whh1r;
#pragma unroll
            for (int k = 0; k < 32; k++) {
                wA[k] = w1[lane * 32 + k];
                wB[k] = w1[(lane + 64) * 32 + k];
            }
        }
        if (lane < 32) zp[lane] = 0.f;
        __threadfence_block();
        float c = 0.f;
        for (int t = 0; t < 12; t++) {
            float d0 = zs1[t * 128 + lane], d1 = zs1[t * 128 + 64 + lane];
#pragma unroll
            for (int k = 0; k < 8; k++) {
                float4 h4 = *(const float4*)&zp[4 * k];
                d0 += wA[4*k]*h4.x + wA[4*k+1]*h4.y + wA[4*k+2]*h4.z + wA[4*k+3]*h4.w;
                d1 += wB[4*k]*h4.x + wB[4*k+1]*h4.y + wB[4*k+2]*h4.z + wB[4*k+3]*h4.w;
            }
            float e0 = __shfl_xor(d0, 32, 64);
            float e1 = __shfl_xor(d1, 32, 64);
            if (lane < 32) {
                c = sigmf(e0) * c + sigmf(d0) * tanhf(d1);
                float h = sigmf(e1) * tanhf(c);
                zp[lane] = h;
                h1s[t * 32 + lane] = h;
            }
            __threadfence_block();
        }
    }
    __syncthreads();

    // ---- Phase C: Wih2 projection from LDS h1 ----
    float zbias = b2i[tid] + b2h[tid];
    if (bf) {
        const uint4* wi = (const uint4*)((const uint16_t*)Wih2r + tid * 32);
        uint4 wa = wi[0], wb = wi[1], wc = wi[2], wd = wi[3];
#pragma unroll
        for (int t = 0; t < 12; t++) {
            const float4* hp = (const float4*)&h1s[t * 32];
            float4 h0 = hp[0], h1 = hp[1], h2 = hp[2], h3 = hp[3];
            float4 h4 = hp[4], h5 = hp[5], h6 = hp[6], h7 = hp[7];
            float z = zbias;
            z += bflo(wa.x)*h0.x + bfhi(wa.x)*h0.y + bflo(wa.y)*h0.z + bfhi(wa.y)*h0.w;
            z += bflo(wa.z)*h1.x + bfhi(wa.z)*h1.y + bflo(wa.w)*h1.z + bfhi(wa.w)*h1.w;
            z += bflo(wb.x)*h2.x + bfhi(wb.x)*h2.y + bflo(wb.y)*h2.z + bfhi(wb.y)*h2.w;
            z += bflo(wb.z)*h3.x + bfhi(wb.z)*h3.y + bflo(wb.w)*h3.z + bfhi(wb.w)*h3.w;
            z += bflo(wc.x)*h4.x + bfhi(wc.x)*h4.y + bflo(wc.y)*h4.z + bfhi(wc.y)*h4.w;
            z += bflo(wc.z)*h5.x + bfhi(wc.z)*h5.y + bflo(wc.w)*h5.z + bfhi(wc.w)*h5.w;
            z += bflo(wd.x)*h6.x + bfhi(wd.x)*h6.y + bflo(wd.y)*h6.z + bfhi(wd.y)*h6.w;
            z += bflo(wd.z)*h7.x + bfhi(wd.z)*h7.y + bflo(wd.w)*h7.z + bfhi(wd.w)*h7.w;
            zs2[t * 512 + tid] = z;
        }
    } else {
        const float4* wi = (const float4*)((const float*)Wih2r + tid * 32);
        float4 w0 = wi[0], w1 = wi[1], w2 = wi[2], w3 = wi[3];
        float4 w4 = wi[4], w5 = wi[5], w6 = wi[6], w7 = wi[7];
#pragma unroll
        for (int t = 0; t < 12; t++) {
            const float4* hp = (const float4*)&h1s[t * 32];
            float4 h0 = hp[0], h1 = hp[1], h2 = hp[2], h3 = hp[3];
            float4 h4 = hp[4], h5 = hp[5], h6 = hp[6], h7 = hp[7];
            float z = zbias;
            z += w0.x*h0.x + w0.y*h0.y + w0.z*h0.z + w0.w*h0.w;
            z += w1.x*h1.x + w1.y*h1.y + w1.z*h1.z + w1.w*h1.w;
            z += w2.x*h2.x + w2.y*h2.y + w2.z*h2.z + w2.w*h2.w;
            z += w3.x*h3.x + w3.y*h3.y + w3.z*h3.z + w3.w*h3.w;
            z += w4.x*h4.x + w4.y*h4.y + w4.z*h4.z + w4.w*h4.w;
            z += w5.x*h5.x + w5.y*h5.y + w5.z*h5.z + w5.w*h5.w;
            z += w6.x*h6.x + w6.y*h6.y + w6.z*h6.z + w6.w*h6.w;
            z += w7.x*h7.x + w7.y*h7.y + w7.z*h7.z + w7.w*h7.w;
            zs2[t * 512 + tid] = z;
        }
    }

    // ---- Phase D: LSTM2 recurrence (pinned weights, b128 LDS reads) ----
    uint4 wreg[16];
    if (bf) {
        const uint4* p = (const uint4*)((const uint16_t*)Whh2r + tid * 128);
#pragma unroll
        for (int k = 0; k < 16; k++) wreg[k] = p[k];
    }
    const float4* wf = (const float4*)((const float*)Whh2r + tid * 128);
    if (tid < 128) hb[tid] = 0.f;
    float c2 = 0.f;
    __syncthreads();
    for (int t = 0; t < 12; t++) {
        float p0 = 0.f, p1 = 0.f, p2 = 0.f, p3 = 0.f;
        if (bf) {
#pragma unroll
            for (int k = 0; k < 8; k++) {
                float4 h0 = *(const float4*)&hb[16 * k];
                float4 h1 = *(const float4*)&hb[16 * k + 4];
                float4 h2 = *(const float4*)&hb[16 * k + 8];
                float4 h3 = *(const float4*)&hb[16 * k + 12];
                uint4 ua = wreg[2 * k], ub = wreg[2 * k + 1];
                p0 += bflo(ua.x)*h0.x + bfhi(ua.x)*h0.y + bflo(ua.y)*h0.z + bfhi(ua.y)*h0.w;
                p1 += bflo(ua.z)*h1.x + bfhi(ua.z)*h1.y + bflo(ua.w)*h1.z + bfhi(ua.w)*h1.w;
                p2 += bflo(ub.x)*h2.x + bfhi(ub.x)*h2.y + bflo(ub.y)*h2.z + bfhi(ub.y)*h2.w;
                p3 += bflo(ub.z)*h3.x + bfhi(ub.z)*h3.y + bflo(ub.w)*h3.z + bfhi(ub.w)*h3.w;
            }
        } else {
#pragma unroll
            for (int k = 0; k < 8; k++) {
                float4 h0 = *(const float4*)&hb[16 * k];
                float4 h1 = *(const float4*)&hb[16 * k + 4];
                float4 h2 = *(const float4*)&hb[16 * k + 8];
                float4 h3 = *(const float4*)&hb[16 * k + 12];
                float4 q0 = wf[4 * k], q1 = wf[4 * k + 1], q2 = wf[4 * k + 2], q3 = wf[4 * k + 3];
                p0 += q0.x*h0.x + q0.y*h0.y + q0.z*h0.z + q0.w*h0.w;
                p1 += q1.x*h1.x + q1.y*h1.y + q1.z*h1.z + q1.w*h1.w;
                p2 += q2.x*h2.x + q2.y*h2.y + q2.z*h2.z + q2.w*h2.w;
                p3 += q3.x*h3.x + q3.y*h3.y + q3.z*h3.z + q3.w*h3.w;
            }
        }
        zb[tid] = zs2[t * 512 + tid] + (p0 + p1) + (p2 + p3);
        __syncthreads();
        if (tid < 128) {
            float iv = zb[tid], fv = zb[128 + tid], gv = zb[256 + tid], ov = zb[384 + tid];
            c2 = sigmf(fv) * c2 + sigmf(iv) * tanhf(gv);
            float h = sigmf(ov) * tanhf(c2);
            hb[tid] = h;
            if (t == 11) h2l[b * 128 + tid] = h;
        }
        __syncthreads();
    }
}

// ---------- final linear (dual-path W) ----------
__global__ void __launch_bounds__(256) k_lin(const float* __restrict__ h2l,
                                             const void* __restrict__ Wraw,
                                             const float* __restrict__ bl,
                                             const int* __restrict__ flags,
                                             void* __restrict__ outv) {
    __shared__ float hl[8 * 128];
    int bg = blockIdx.y;
    for (int i = threadIdx.x; i < 1024; i += 256) hl[i] = h2l[bg * 1024 + i];
    __syncthreads();
    int o = blockIdx.x * 256 + threadIdx.x;
    float bb = bl[o];
    float acc[8];
#pragma unroll
    for (int b = 0; b < 8; b++) acc[b] = bb;
    int bf = flags[0];
    if (bf) {
        const uint4* wp = (const uint4*)((const uint16_t*)Wraw + o * 128);
        for (int k = 0; k < 16; k++) {
            uint4 u = wp[k];
            float w0 = bflo(u.x), w1 = bfhi(u.x), w2 = bflo(u.y), w3 = bfhi(u.y);
            float w4 = bflo(u.z), w5 = bfhi(u.z), w6 = bflo(u.w), w7 = bfhi(u.w);
#pragma unroll
            for (int b = 0; b < 8; b++) {
                const float* h8 = hl + b * 128 + k * 8;
                acc[b] += w0 * h8[0] + w1 * h8[1] + w2 * h8[2] + w3 * h8[3]
                        + w4 * h8[4] + w5 * h8[5] + w6 * h8[6] + w7 * h8[7];
            }
        }
    } else {
        const float4* wp = (const float4*)((const float*)Wraw + o * 128);
        for (int k = 0; k < 32; k++) {
            float4 w = wp[k];
#pragma unroll
            for (int b = 0; b < 8; b++) {
                const float* h4 = hl + b * 128 + k * 4;
                acc[b] += w.x * h4[0] + w.y * h4[1] + w.z * h4[2] + w.w * h4[3];
            }
        }
    }
    if (bf) {
        uint16_t* out = (uint16_t*)outv;
#pragma unroll
        for (int b = 0; b < 8; b++) out[(bg * 8 + b) * 18432 + o] = f2bf(acc[b]);
    } else {
        float* out = (float*)outv;
#pragma unroll
        for (int b = 0; b < 8; b++) out[(bg * 8 + b) * 18432 + o] = acc[b];
    }
}

extern "C" void kernel_launch(void* const* d_in, const int* in_sizes, int n_in,
                              void* d_out, int out_size, void* d_ws, size_t ws_size,
                              hipStream_t stream) {
    int E = in_sizes[1] / 2;

    float* ws = (float*)d_ws;
    int* flags = (int*)ws;          // [0]=bf16 [1]=stride [2]=gcount
    float* cWg   = ws + O_WG;
    float* cAtt  = ws + O_AS;
    float* cBias = ws + O_BIAS;
    float* cBih1 = ws + O_BIH1;
    float* cBhh1 = ws + O_BHH1;
    float* cBih2 = ws + O_BIH2;
    float* cBhh2 = ws + O_BHH2;
    float* cBlin = ws + O_BLIN;

    float* base = ws + O_END;
    float* a_s  = base;                            // 524288
    float* a_d  = a_s + 524288;                    // 524288
    int* deg    = (int*)(a_d + 524288);            // 65536
    int* offs   = deg + 65536;                     // 65536
    int* rank   = offs + 65536;                    // E
    int* ssrc   = rank + E;                        // E
    float* gT   = (float*)(ssrc + E);              // 786432
    float* h2l  = gT + 786432;                     // 4096
    size_t needed = (size_t)((h2l + 4096) - ws) * 4;
    if (ws_size < needed) return;

    k_pre<<<256, 256, 0, stream>>>(d_in[0], (const int*)d_in[1],
                                   d_in[2], d_in[3], d_in[4], d_in[5],
                                   d_in[8], d_in[9], d_in[12], d_in[13], d_in[15],
                                   ws, deg);
    k_nfa<<<2048, 256, 0, stream>>>(d_in[0], cWg, cAtt, flags,
                                    (const int*)d_in[1], E, deg, rank,
                                    a_s, a_d);
    k_scan<<<256, 256, 0, stream>>>(deg, offs, flags + 2);
    k_scatter<<<(E + 255) / 256, 256, 0, stream>>>((const int*)d_in[1], E, flags,
                                                   offs, rank, ssrc);
    k_agg<<<NTOT / 4, 256, 0, stream>>>(d_in[0], cWg, a_s, a_d, offs, deg, ssrc,
                                        cBias, flags, gT);
    k_tail<<<32, 512, 0, stream>>>(gT, d_in[6], cBih1, cBhh1, d_in[7],
                                   d_in[10], d_in[11], cBih2, cBhh2, flags, h2l);
    k_lin<<<dim3(72, 4), 256, 0, stream>>>(h2l, d_in[14], cBlin, flags, d_out);
}

// Round 14
// 385.020 us; speedup vs baseline: 1.8019x; 1.8019x over previous
//
#include <hip/hip_runtime.h>
#include <hip/hip_bf16.h>
#include <stdint.h>

#define NTOT 65536   // B * N_NODE
#define NNODE 2048
#define CIN 12

__device__ __forceinline__ float bf2f(uint32_t u) {
    union { uint32_t i; float f; } v; v.i = u << 16; return v.f;
}
__device__ __forceinline__ uint16_t f2bf(float f) {
    union { float f; uint32_t i; } v; v.f = f;
    uint32_t x = v.i;
    uint32_t r = x + 0x7fffu + ((x >> 16) & 1u);
    return (uint16_t)(r >> 16);
}
__device__ __forceinline__ float bflo(uint32_t u) { return bf2f(u & 0xffffu); }
__device__ __forceinline__ float bfhi(uint32_t u) { return bf2f(u >> 16); }
__device__ __forceinline__ float sigmf(float x) { return 1.0f / (1.0f + __expf(-x)); }
__device__ __forceinline__ float lrelu(float v) { return v > 0.f ? v : 0.2f * v; }

// ws float offsets (flags[0]=bf16?, flags[1]=edge stride words, flags[2]=gcount)
#define O_WG   16
#define O_AS   1168
#define O_AD   1264
#define O_BIAS 1360
#define O_BIH1 1376
#define O_BHH1 1504
#define O_BIH2 1632
#define O_BHH2 2144
#define O_BLIN 2656
#define O_END  21088

__device__ __forceinline__ void cvt(const void* s, float* d, int i, int bf) {
    d[i] = bf ? bf2f(((const uint16_t*)s)[i]) : ((const float*)s)[i];
}

// ---------- fused: dtype detect + small-tensor conv + zero ----------
__global__ void __launch_bounds__(256) k_pre(
    const void* x, const int* __restrict__ e32,
    const void* wg, const void* as_, const void* ad_, const void* bs,
    const void* b1, const void* bb1, const void* b2, const void* bb2,
    const void* bl, float* __restrict__ ws, int* __restrict__ deg) {
    int tid = threadIdx.x, lane = tid & 63;
    uint32_t u = ((const uint16_t*)x)[2 * lane];
    uint32_t ex = (u >> 7) & 0xFF;
    bool sane = (ex >= 0x60 && ex <= 0x9F) || (u == 0);
    unsigned long long bsx = __ballot(sane);
    bool hi_zero = (e32[2 * lane + 1] == 0);
    unsigned long long bz = __ballot(hi_zero);
    int bf = (__popcll(bsx) >= 52) ? 1 : 0;
    int st = (__popcll(bz) == 64) ? 2 : 1;
    if (blockIdx.x == 0 && tid == 0) {
        ((int*)ws)[0] = bf; ((int*)ws)[1] = st; ((int*)ws)[2] = 0;
    }
    deg[blockIdx.x * 256 + tid] = 0;
    int i = blockIdx.x * 256 + tid;
    if (i < 1152)  { cvt(wg,  ws + O_WG,   i, bf); return; } i -= 1152;
    if (i < 96)    { cvt(as_, ws + O_AS,   i, bf); return; } i -= 96;
    if (i < 96)    { cvt(ad_, ws + O_AD,   i, bf); return; } i -= 96;
    if (i < 12)    { cvt(bs,  ws + O_BIAS, i, bf); return; } i -= 12;
    if (i < 128)   { cvt(b1,  ws + O_BIH1, i, bf); return; } i -= 128;
    if (i < 128)   { cvt(bb1, ws + O_BHH1, i, bf); return; } i -= 128;
    if (i < 512)   { cvt(b2,  ws + O_BIH2, i, bf); return; } i -= 512;
    if (i < 512)   { cvt(bb2, ws + O_BHH2, i, bf); return; } i -= 512;
    if (i < 18432) { cvt(bl,  ws + O_BLIN, i, bf); }
}

// ---------- fused attention scores + edge histogram ----------
__global__ void __launch_bounds__(256) k_nfa(const void* __restrict__ xraw,
                                             const float* __restrict__ Wg,
                                             const float* __restrict__ att,
                                             const int* __restrict__ flags,
                                             const int* __restrict__ e, int E,
                                             int* __restrict__ deg, int* __restrict__ rank,
                                             float* __restrict__ a_s, float* __restrict__ a_d) {
    __shared__ float sx[384];
    __shared__ float sw[1152];
    __shared__ float satt[192];
    __shared__ float sh[3072];
    int tid = threadIdx.x;
    int n0 = blockIdx.x * 32;
    if (flags[0]) {
        const uint32_t* xp = (const uint32_t*)xraw;
        for (int i = tid; i < 192; i += 256) {
            uint32_t u = xp[n0 * 6 + i];
            sx[2 * i] = bflo(u); sx[2 * i + 1] = bfhi(u);
        }
    } else {
        const float* xp = (const float*)xraw;
        for (int i = tid; i < 384; i += 256) sx[i] = xp[n0 * 12 + i];
    }
    for (int i = tid; i < 1152; i += 256) sw[i] = Wg[i];
    if (tid < 192) satt[tid] = att[tid];
    {
        long st = flags[1];
        int chunk = (E + gridDim.x - 1) / gridDim.x;
        int ebase = blockIdx.x * chunk;
        int eend = min(ebase + chunk, E);
        for (int i = ebase + tid; i < eend; i += 256) {
            int d = e[st * (E + i)];
            rank[i] = atomicAdd(&deg[d], 1);
        }
    }
    __syncthreads();
#pragma unroll
    for (int r = 0; r < 12; r++) {
        int idx = r * 256 + tid;
        int n = idx / 96, o = idx % 96;
        float acc = 0.f;
#pragma unroll
        for (int k = 0; k < 12; k++) acc += sx[n * 12 + k] * sw[k * 96 + o];
        sh[idx] = acc;
    }
    __syncthreads();
    {
        int nl = tid >> 3, h = tid & 7;
        const float* hr = sh + nl * 96 + h * 12;
        float s = 0.f, dd = 0.f;
#pragma unroll
        for (int c = 0; c < 12; c++) {
            float v = hr[c];
            s += v * satt[h * 12 + c];
            dd += v * satt[96 + h * 12 + c];
        }
        a_s[n0 * 8 + tid] = s;
        a_d[n0 * 8 + tid] = dd;
    }
}

// ---------- scan: local exclusive scan + atomic global base ----------
__global__ void k_scan(const int* __restrict__ deg, int* __restrict__ offs,
                       int* __restrict__ gcount) {
    __shared__ int s[256];
    __shared__ int base;
    int t = threadIdx.x, i = blockIdx.x * 256 + t;
    int v = deg[i];
    s[t] = v; __syncthreads();
    for (int off = 1; off < 256; off <<= 1) {
        int a = (t >= off) ? s[t - off] : 0;
        __syncthreads();
        s[t] += a;
        __syncthreads();
    }
    if (t == 255) base = atomicAdd(gcount, s[255]);
    __syncthreads();
    offs[i] = base + s[t] - v;
}

__global__ void k_scatter(const int* __restrict__ e, int E, const int* __restrict__ flags,
                          const int* __restrict__ offs, const int* __restrict__ rank,
                          int* __restrict__ ssrc) {
    int i = blockIdx.x * 256 + threadIdx.x;
    if (i < E) {
        long st = flags[1];
        int s = e[st * i];
        int d = e[st * (E + i)];
        ssrc[offs[d] + rank[i]] = s;
    }
}

// ---------- GAT aggregation: aggregate x (12ch), project through Wg per node ----------
__global__ void __launch_bounds__(256) k_agg(
    const void* __restrict__ xraw, const float* __restrict__ WgG,
    const float* __restrict__ a_s, const float* __restrict__ a_d,
    const int* __restrict__ offs, const int* __restrict__ deg,
    const int* __restrict__ ssrc, const float* __restrict__ bias,
    const int* __restrict__ flags, float* __restrict__ gT) {
    __shared__ float swg[1152];
    __shared__ float sres[4][12];
    int tid = threadIdx.x, wave = tid >> 6, lane = tid & 63;
    for (int i = tid; i < 1152; i += 256) swg[i] = WgG[i];
    __syncthreads();
    int node = blockIdx.x * 4 + wave;
    int beg = offs[node], d = deg[node];
    int sub = lane >> 3, h = lane & 7;
    float adh = a_d[node * 8 + h];
    int bf = flags[0];
    float acc[12];
    float wsum = 0.f;
#pragma unroll
    for (int c = 0; c < 12; c++) acc[c] = 0.f;
    if (sub == 0) {
        float w = __expf(lrelu(a_s[node * 8 + h] + adh));
        wsum = w;
        if (bf) {
            const uint2* xp = (const uint2*)((const uint16_t*)xraw + node * 12);
            uint2 u0 = xp[0], u1 = xp[1], u2 = xp[2];
            acc[0] = w * bflo(u0.x); acc[1] = w * bfhi(u0.x);
            acc[2] = w * bflo(u0.y); acc[3] = w * bfhi(u0.y);
            acc[4] = w * bflo(u1.x); acc[5] = w * bfhi(u1.x);
            acc[6] = w * bflo(u1.y); acc[7] = w * bfhi(u1.y);
            acc[8] = w * bflo(u2.x); acc[9] = w * bfhi(u2.x);
            acc[10] = w * bflo(u2.y); acc[11] = w * bfhi(u2.y);
        } else {
            const float4* xp = (const float4*)((const float*)xraw + node * 12);
            float4 v0 = xp[0], v1 = xp[1], v2 = xp[2];
            acc[0] = w * v0.x; acc[1] = w * v0.y; acc[2] = w * v0.z; acc[3] = w * v0.w;
            acc[4] = w * v1.x; acc[5] = w * v1.y; acc[6] = w * v1.z; acc[7] = w * v1.w;
            acc[8] = w * v2.x; acc[9] = w * v2.y; acc[10] = w * v2.z; acc[11] = w * v2.w;
        }
    }
    for (int base = 0; base < d; base += 8) {
        int k = base + sub;
        if (k < d) {
            int s = ssrc[beg + k];
            float w = __expf(lrelu(a_s[s * 8 + h] + adh));
            wsum += w;
            if (bf) {
                const uint2* xp = (const uint2*)((const uint16_t*)xraw + s * 12);
                uint2 u0 = xp[0], u1 = xp[1], u2 = xp[2];
                acc[0] += w * bflo(u0.x); acc[1] += w * bfhi(u0.x);
                acc[2] += w * bflo(u0.y); acc[3] += w * bfhi(u0.y);
                acc[4] += w * bflo(u1.x); acc[5] += w * bfhi(u1.x);
                acc[6] += w * bflo(u1.y); acc[7] += w * bfhi(u1.y);
                acc[8] += w * bflo(u2.x); acc[9] += w * bfhi(u2.x);
                acc[10] += w * bflo(u2.y); acc[11] += w * bfhi(u2.y);
            } else {
                const float4* xp = (const float4*)((const float*)xraw + s * 12);
                float4 v0 = xp[0], v1 = xp[1], v2 = xp[2];
                acc[0] += w * v0.x; acc[1] += w * v0.y; acc[2] += w * v0.z; acc[3] += w * v0.w;
                acc[4] += w * v1.x; acc[5] += w * v1.y; acc[6] += w * v1.z; acc[7] += w * v1.w;
                acc[8] += w * v2.x; acc[9] += w * v2.y; acc[10] += w * v2.z; acc[11] += w * v2.w;
            }
        }
    }
#pragma unroll
    for (int off = 8; off <= 32; off <<= 1) {
        wsum += __shfl_xor(wsum, off, 64);
#pragma unroll
        for (int c = 0; c < 12; c++) acc[c] += __shfl_xor(acc[c], off, 64);
    }
    float invw = 1.f / wsum;
#pragma unroll
    for (int c = 0; c < 12; c++) acc[c] *= invw;
    float p0 = 0.f, p1 = 0.f;
    const float* wcol = swg + h * 12;
#pragma unroll
    for (int k = 0; k < 12; k++) {
        float a = acc[k];
        p0 += a * wcol[k * 96 + sub];
        p1 += a * wcol[k * 96 + sub + 4];
    }
#pragma unroll
    for (int off = 1; off <= 4; off <<= 1) {
        p0 += __shfl_xor(p0, off, 64);
        p1 += __shfl_xor(p1, off, 64);
    }
    if (h == 0) {
        sres[wave][sub] = p0;
        if (sub >= 4) sres[wave][sub + 4] = p1;
    }
    __syncthreads();
    if (tid < 48) {
        int no = tid / 12, c = tid % 12;
        gT[c * NTOT + blockIdx.x * 4 + no] = sres[no][c] * 0.125f + bias[c];
    }
}

// ---------- Z1: 4 batches per block, weight loads shared ----------
__global__ void __launch_bounds__(256) k_z1(const float* __restrict__ gT,
                                            const void* __restrict__ Wraw,
                                            const float* __restrict__ b1,
                                            const float* __restrict__ b2,
                                            const int* __restrict__ flags,
                                            float* __restrict__ Z1) {
    int t = blockIdx.x >> 3, bg = (blockIdx.x & 7) * 4;
    __shared__ float sv[4][2048];
    __shared__ float zp[2][4][128];
    int tid = threadIdx.x;
#pragma unroll
    for (int q = 0; q < 4; q++)
        for (int v = tid; v < 2048; v += 256) sv[q][v] = gT[t * NTOT + (bg + q) * NNODE + v];
    __syncthreads();
    int row = tid & 127, half = tid >> 7;
    float a0 = 0.f, a1 = 0.f, a2 = 0.f, a3 = 0.f;
    int hbase = half * 1024;
    if (flags[0]) {
        const uint4* wp = (const uint4*)((const uint16_t*)Wraw + row * 2048 + hbase);
        for (int k = 0; k < 128; k++) {
            uint4 u = wp[k];
            float w0 = bflo(u.x), w1 = bfhi(u.x), w2 = bflo(u.y), w3 = bfhi(u.y);
            float w4 = bflo(u.z), w5 = bfhi(u.z), w6 = bflo(u.w), w7 = bfhi(u.w);
#pragma unroll
            for (int q = 0; q < 4; q++) {
                float4 A = *(const float4*)&sv[q][hbase + 8 * k];
                float4 B = *(const float4*)&sv[q][hbase + 8 * k + 4];
                float r = w0 * A.x + w1 * A.y + w2 * A.z + w3 * A.w
                        + w4 * B.x + w5 * B.y + w6 * B.z + w7 * B.w;
                if (q == 0) a0 += r; else if (q == 1) a1 += r;
                else if (q == 2) a2 += r; else a3 += r;
            }
        }
    } else {
        const float4* wp = (const float4*)((const float*)Wraw + row * 2048 + hbase);
        for (int k = 0; k < 256; k++) {
            float4 w = wp[k];
#pragma unroll
            for (int q = 0; q < 4; q++) {
                float4 A = *(const float4*)&sv[q][hbase + 4 * k];
                float r = w.x * A.x + w.y * A.y + w.z * A.z + w.w * A.w;
                if (q == 0) a0 += r; else if (q == 1) a1 += r;
                else if (q == 2) a2 += r; else a3 += r;
            }
        }
    }
    zp[half][0][row] = a0; zp[half][1][row] = a1;
    zp[half][2][row] = a2; zp[half][3][row] = a3;
    __syncthreads();
    if (tid < 128) {
        float bb = b1[tid] + b2[tid];
#pragma unroll
        for (int q = 0; q < 4; q++)
            Z1[t * 4096 + (bg + q) * 128 + tid] = zp[0][q][tid] + zp[1][q][tid] + bb;
    }
}

// ---------- fused tail: LSTM1 (single wave) + Wih2 proj + LSTM2, one block/batch ----------
__global__ void __launch_bounds__(512) k_tail(
    const float* __restrict__ Z1,
    const void* __restrict__ Whh1r,
    const void* __restrict__ Wih2r, const void* __restrict__ Whh2r,
    const float* __restrict__ b2i, const float* __restrict__ b2h,
    const int* __restrict__ flags, float* __restrict__ h2l) {
    int b = blockIdx.x, tid = threadIdx.x;
    __shared__ __align__(16) float h1s[12 * 32];
    __shared__ __align__(16) float hb1[32];
    __shared__ float zs2[12 * 512];
    __shared__ __align__(16) float hb[128];
    __shared__ float zb[512];
    int bf = flags[0];

    // ---- Phase B: LSTM1 recurrence on wave 0 (zero barriers) ----
    if (tid < 64) {
        int lane = tid;
        float wA[32], wB[32];
        if (bf) {
            const uint32_t* w1 = (const uint32_t*)Whh1r;
#pragma unroll
            for (int k = 0; k < 16; k++) {
                uint32_t u = w1[lane * 16 + k];
                wA[2 * k] = bflo(u); wA[2 * k + 1] = bfhi(u);
                uint32_t v = w1[(lane + 64) * 16 + k];
                wB[2 * k] = bflo(v); wB[2 * k + 1] = bfhi(v);
            }
        } else {
            const float* w1 = (const float*)Whh1r;
#pragma unroll
            for (int k = 0; k < 32; k++) {
                wA[k] = w1[lane * 32 + k];
                wB[k] = w1[(lane + 64) * 32 + k];
            }
        }
        float za[12], zg[12];
#pragma unroll
        for (int t = 0; t < 12; t++) {
            za[t] = Z1[t * 4096 + b * 128 + lane];
            zg[t] = Z1[t * 4096 + b * 128 + 64 + lane];
        }
        if (lane < 32) hb1[lane] = 0.f;
        __threadfence_block();
        float c = 0.f;
        for (int t = 0; t < 12; t++) {
            float d0 = za[t], d1 = zg[t];
#pragma unroll
            for (int k = 0; k < 8; k++) {
                float4 h4 = *(const float4*)&hb1[4 * k];
                d0 += wA[4*k]*h4.x + wA[4*k+1]*h4.y + wA[4*k+2]*h4.z + wA[4*k+3]*h4.w;
                d1 += wB[4*k]*h4.x + wB[4*k+1]*h4.y + wB[4*k+2]*h4.z + wB[4*k+3]*h4.w;
            }
            float e0 = __shfl_xor(d0, 32, 64);
            float e1 = __shfl_xor(d1, 32, 64);
            if (lane < 32) {
                c = sigmf(e0) * c + sigmf(d0) * tanhf(d1);
                float h = sigmf(e1) * tanhf(c);
                hb1[lane] = h;
                h1s[t * 32 + lane] = h;
            }
            __threadfence_block();
        }
    }
    __syncthreads();

    // ---- Phase C: Wih2 projection from LDS h1 ----
    float zbias = b2i[tid] + b2h[tid];
    if (bf) {
        const uint4* wi = (const uint4*)((const uint16_t*)Wih2r + tid * 32);
        uint4 wa = wi[0], wb = wi[1], wc = wi[2], wd = wi[3];
#pragma unroll
        for (int t = 0; t < 12; t++) {
            const float4* hp = (const float4*)&h1s[t * 32];
            float4 h0 = hp[0], h1 = hp[1], h2 = hp[2], h3 = hp[3];
            float4 h4 = hp[4], h5 = hp[5], h6 = hp[6], h7 = hp[7];
            float z = zbias;
            z += bflo(wa.x)*h0.x + bfhi(wa.x)*h0.y + bflo(wa.y)*h0.z + bfhi(wa.y)*h0.w;
            z += bflo(wa.z)*h1.x + bfhi(wa.z)*h1.y + bflo(wa.w)*h1.z + bfhi(wa.w)*h1.w;
            z += bflo(wb.x)*h2.x + bfhi(wb.x)*h2.y + bflo(wb.y)*h2.z + bfhi(wb.y)*h2.w;
            z += bflo(wb.z)*h3.x + bfhi(wb.z)*h3.y + bflo(wb.w)*h3.z + bfhi(wb.w)*h3.w;
            z += bflo(wc.x)*h4.x + bfhi(wc.x)*h4.y + bflo(wc.y)*h4.z + bfhi(wc.y)*h4.w;
            z += bflo(wc.z)*h5.x + bfhi(wc.z)*h5.y + bflo(wc.w)*h5.z + bfhi(wc.w)*h5.w;
            z += bflo(wd.x)*h6.x + bfhi(wd.x)*h6.y + bflo(wd.y)*h6.z + bfhi(wd.y)*h6.w;
            z += bflo(wd.z)*h7.x + bfhi(wd.z)*h7.y + bflo(wd.w)*h7.z + bfhi(wd.w)*h7.w;
            zs2[t * 512 + tid] = z;
        }
    } else {
        const float4* wi = (const float4*)((const float*)Wih2r + tid * 32);
        float4 w0 = wi[0], w1 = wi[1], w2 = wi[2], w3 = wi[3];
        float4 w4 = wi[4], w5 = wi[5], w6 = wi[6], w7 = wi[7];
#pragma unroll
        for (int t = 0; t < 12; t++) {
            const float4* hp = (const float4*)&h1s[t * 32];
            float4 h0 = hp[0], h1 = hp[1], h2 = hp[2], h3 = hp[3];
            float4 h4 = hp[4], h5 = hp[5], h6 = hp[6], h7 = hp[7];
            float z = zbias;
            z += w0.x*h0.x + w0.y*h0.y + w0.z*h0.z + w0.w*h0.w;
            z += w1.x*h1.x + w1.y*h1.y + w1.z*h1.z + w1.w*h1.w;
            z += w2.x*h2.x + w2.y*h2.y + w2.z*h2.z + w2.w*h2.w;
            z += w3.x*h3.x + w3.y*h3.y + w3.z*h3.z + w3.w*h3.w;
            z += w4.x*h4.x + w4.y*h4.y + w4.z*h4.z + w4.w*h4.w;
            z += w5.x*h5.x + w5.y*h5.y + w5.z*h5.z + w5.w*h5.w;
            z += w6.x*h6.x + w6.y*h6.y + w6.z*h6.z + w6.w*h6.w;
            z += w7.x*h7.x + w7.y*h7.y + w7.z*h7.z + w7.w*h7.w;
            zs2[t * 512 + tid] = z;
        }
    }

    // ---- Phase D: LSTM2 recurrence (pinned weights, b128 LDS reads) ----
    uint4 wreg[16];
    if (bf) {
        const uint4* p = (const uint4*)((const uint16_t*)Whh2r + tid * 128);
#pragma unroll
        for (int k = 0; k < 16; k++) wreg[k] = p[k];
    }
    const float4* wf = (const float4*)((const float*)Whh2r + tid * 128);
    if (tid < 128) hb[tid] = 0.f;
    float c2 = 0.f;
    __syncthreads();
    for (int t = 0; t < 12; t++) {
        float p0 = 0.f, p1 = 0.f, p2 = 0.f, p3 = 0.f;
        if (bf) {
#pragma unroll
            for (int k = 0; k < 8; k++) {
                float4 h0 = *(const float4*)&hb[16 * k];
                float4 h1 = *(const float4*)&hb[16 * k + 4];
                float4 h2 = *(const float4*)&hb[16 * k + 8];
                float4 h3 = *(const float4*)&hb[16 * k + 12];
                uint4 ua = wreg[2 * k], ub = wreg[2 * k + 1];
                p0 += bflo(ua.x)*h0.x + bfhi(ua.x)*h0.y + bflo(ua.y)*h0.z + bfhi(ua.y)*h0.w;
                p1 += bflo(ua.z)*h1.x + bfhi(ua.z)*h1.y + bflo(ua.w)*h1.z + bfhi(ua.w)*h1.w;
                p2 += bflo(ub.x)*h2.x + bfhi(ub.x)*h2.y + bflo(ub.y)*h2.z + bfhi(ub.y)*h2.w;
                p3 += bflo(ub.z)*h3.x + bfhi(ub.z)*h3.y + bflo(ub.w)*h3.z + bfhi(ub.w)*h3.w;
            }
        } else {
#pragma unroll
            for (int k = 0; k < 8; k++) {
                float4 h0 = *(const float4*)&hb[16 * k];
                float4 h1 = *(const float4*)&hb[16 * k + 4];
                float4 h2 = *(const float4*)&hb[16 * k + 8];
                float4 h3 = *(const float4*)&hb[16 * k + 12];
                float4 q0 = wf[4 * k], q1 = wf[4 * k + 1], q2 = wf[4 * k + 2], q3 = wf[4 * k + 3];
                p0 += q0.x*h0.x + q0.y*h0.y + q0.z*h0.z + q0.w*h0.w;
                p1 += q1.x*h1.x + q1.y*h1.y + q1.z*h1.z + q1.w*h1.w;
                p2 += q2.x*h2.x + q2.y*h2.y + q2.z*h2.z + q2.w*h2.w;
                p3 += q3.x*h3.x + q3.y*h3.y + q3.z*h3.z + q3.w*h3.w;
            }
        }
        zb[tid] = zs2[t * 512 + tid] + (p0 + p1) + (p2 + p3);
        __syncthreads();
        if (tid < 128) {
            float iv = zb[tid], fv = zb[128 + tid], gv = zb[256 + tid], ov = zb[384 + tid];
            c2 = sigmf(fv) * c2 + sigmf(iv) * tanhf(gv);
            float h = sigmf(ov) * tanhf(c2);
            hb[tid] = h;
            if (t == 11) h2l[b * 128 + tid] = h;
        }
        __syncthreads();
    }
}

// ---------- final linear (dual-path W) ----------
__global__ void __launch_bounds__(256) k_lin(const float* __restrict__ h2l,
                                             const void* __restrict__ Wraw,
                                             const float* __restrict__ bl,
                                             const int* __restrict__ flags,
                                             void* __restrict__ outv) {
    __shared__ float hl[8 * 128];
    int bg = blockIdx.y;
    for (int i = threadIdx.x; i < 1024; i += 256) hl[i] = h2l[bg * 1024 + i];
    __syncthreads();
    int o = blockIdx.x * 256 + threadIdx.x;
    float bb = bl[o];
    float acc[8];
#pragma unroll
    for (int b = 0; b < 8; b++) acc[b] = bb;
    int bf = flags[0];
    if (bf) {
        const uint4* wp = (const uint4*)((const uint16_t*)Wraw + o * 128);
        for (int k = 0; k < 16; k++) {
            uint4 u = wp[k];
            float w0 = bflo(u.x), w1 = bfhi(u.x), w2 = bflo(u.y), w3 = bfhi(u.y);
            float w4 = bflo(u.z), w5 = bfhi(u.z), w6 = bflo(u.w), w7 = bfhi(u.w);
#pragma unroll
            for (int b = 0; b < 8; b++) {
                const float* h8 = hl + b * 128 + k * 8;
                acc[b] += w0 * h8[0] + w1 * h8[1] + w2 * h8[2] + w3 * h8[3]
                        + w4 * h8[4] + w5 * h8[5] + w6 * h8[6] + w7 * h8[7];
            }
        }
    } else {
        const float4* wp = (const float4*)((const float*)Wraw + o * 128);
        for (int k = 0; k < 32; k++) {
            float4 w = wp[k];
#pragma unroll
            for (int b = 0; b < 8; b++) {
                const float* h4 = hl + b * 128 + k * 4;
                acc[b] += w.x * h4[0] + w.y * h4[1] + w.z * h4[2] + w.w * h4[3];
            }
        }
    }
    if (bf) {
        uint16_t* out = (uint16_t*)outv;
#pragma unroll
        for (int b = 0; b < 8; b++) out[(bg * 8 + b) * 18432 + o] = f2bf(acc[b]);
    } else {
        float* out = (float*)outv;
#pragma unroll
        for (int b = 0; b < 8; b++) out[(bg * 8 + b) * 18432 + o] = acc[b];
    }
}

extern "C" void kernel_launch(void* const* d_in, const int* in_sizes, int n_in,
                              void* d_out, int out_size, void* d_ws, size_t ws_size,
                              hipStream_t stream) {
    int E = in_sizes[1] / 2;

    float* ws = (float*)d_ws;
    int* flags = (int*)ws;          // [0]=bf16 [1]=stride [2]=gcount
    float* cWg   = ws + O_WG;
    float* cAtt  = ws + O_AS;
    float* cBias = ws + O_BIAS;
    float* cBih1 = ws + O_BIH1;
    float* cBhh1 = ws + O_BHH1;
    float* cBih2 = ws + O_BIH2;
    float* cBhh2 = ws + O_BHH2;
    float* cBlin = ws + O_BLIN;

    float* base = ws + O_END;
    float* a_s  = base;                            // 524288
    float* a_d  = a_s + 524288;                    // 524288
    int* deg    = (int*)(a_d + 524288);            // 65536
    int* offs   = deg + 65536;                     // 65536
    int* rank   = offs + 65536;                    // E
    int* ssrc   = rank + E;                        // E
    float* gT   = (float*)(ssrc + E);              // 786432
    float* Z1   = gT + 786432;                     // 49152
    float* h2l  = Z1 + 49152;                      // 4096
    size_t needed = (size_t)((h2l + 4096) - ws) * 4;
    if (ws_size < needed) return;

    k_pre<<<256, 256, 0, stream>>>(d_in[0], (const int*)d_in[1],
                                   d_in[2], d_in[3], d_in[4], d_in[5],
                                   d_in[8], d_in[9], d_in[12], d_in[13], d_in[15],
                                   ws, deg);
    k_nfa<<<2048, 256, 0, stream>>>(d_in[0], cWg, cAtt, flags,
                                    (const int*)d_in[1], E, deg, rank,
                                    a_s, a_d);
    k_scan<<<256, 256, 0, stream>>>(deg, offs, flags + 2);
    k_scatter<<<(E + 255) / 256, 256, 0, stream>>>((const int*)d_in[1], E, flags,
                                                   offs, rank, ssrc);
    k_agg<<<NTOT / 4, 256, 0, stream>>>(d_in[0], cWg, a_s, a_d, offs, deg, ssrc,
                                        cBias, flags, gT);
    k_z1<<<96, 256, 0, stream>>>(gT, d_in[6], cBih1, cBhh1, flags, Z1);
    k_tail<<<32, 512, 0, stream>>>(Z1, d_in[7], d_in[10], d_in[11],
                                   cBih2, cBhh2, flags, h2l);
    k_lin<<<dim3(72, 4), 256, 0, stream>>>(h2l, d_in[14], cBlin, flags, d_out);
}